// Round 1
// baseline (352.898 us; speedup 1.0000x reference)
//
#include <hip/hip_runtime.h>
#include <hip/hip_bf16.h>

// Problem constants (B,L,H,D) = (8,2048,8,64); sample_k = u = 40.
#define BB 8
#define LL 2048
#define HH 8
#define DD 64
#define HD 512      // H*D
#define SK 40       // sample_k
#define UU 40       // top-u
#define NCHUNK 16   // key chunks for flash-decode
#define CHUNK 128   // keys per chunk

// ---------------- workspace layout (bytes) ----------------
// M       : B*H*L floats            = 512 KB   @ 0
// TopIdx  : B*H*40 ints             = 10 KB    @ 512K
// Vmean   : B*H*64 floats           = 16 KB    @ 576K
// mpart   : B*H*40*NCHUNK floats    = 160 KB   @ 640K
// spart   : B*H*40*NCHUNK floats    = 160 KB   @ 832K
// Opart   : B*H*40*NCHUNK*64 floats = 10 MB    @ 1M
static const size_t OFF_M     = 0;
static const size_t OFF_TOP   = 512ull * 1024;
static const size_t OFF_VMEAN = 576ull * 1024;
static const size_t OFF_MPART = 640ull * 1024;
static const size_t OFF_SPART = 832ull * 1024;
static const size_t OFF_OPART = 1024ull * 1024;

// ============ kernel A: M[b,h,q] = max_s(Q.Ksample) - mean_s(Q.Ksample) ============
// block = 128 threads = 8 heads x 16 lanes (float4 per lane). one block per (b,q).
__global__ __launch_bounds__(128) void kA_sample_scores(
    const float* __restrict__ Q, const float* __restrict__ K,
    const int* __restrict__ IS, float* __restrict__ M)
{
    int blk = blockIdx.x;            // b*L + q
    int b = blk >> 11;
    int q = blk & (LL - 1);
    int tid = threadIdx.x;
    int h = tid >> 4;
    int lane = tid & 15;

    __shared__ int sidx[SK];
    if (tid < SK) sidx[tid] = IS[q * SK + tid];
    __syncthreads();

    size_t base = (size_t)b * LL * HD;
    const float4 qv = *(const float4*)(Q + base + (size_t)q * HD + h * DD + lane * 4);

    float mx = -1e30f, sm = 0.f;
#pragma unroll 8
    for (int s = 0; s < SK; ++s) {
        int idx = sidx[s];
        const float4 kv = *(const float4*)(K + base + (size_t)idx * HD + h * DD + lane * 4);
        float p = qv.x * kv.x + qv.y * kv.y + qv.z * kv.z + qv.w * kv.w;
        p += __shfl_xor(p, 1);
        p += __shfl_xor(p, 2);
        p += __shfl_xor(p, 4);
        p += __shfl_xor(p, 8);
        mx = fmaxf(mx, p);
        sm += p;
    }
    if (lane == 0)
        M[((size_t)(b * HH + h)) * LL + q] = mx - sm * (1.0f / SK);
}

// ============ kernel B: top-40 indices of M[bh, :] per (b,h) ============
__global__ __launch_bounds__(256) void kB_topk(
    const float* __restrict__ M, int* __restrict__ TopIdx)
{
    int bh = blockIdx.x;
    int tid = threadIdx.x;
    __shared__ float vals[LL];
    __shared__ float rv[4];
    __shared__ int   ri[4];

    const float* m = M + (size_t)bh * LL;
    for (int i = tid; i < LL; i += 256) vals[i] = m[i];
    __syncthreads();

    for (int it = 0; it < UU; ++it) {
        float bv = -1e30f; int bi = 0x7fffffff;
        for (int i = tid; i < LL; i += 256) {
            float v = vals[i];
            if (v > bv || (v == bv && i < bi)) { bv = v; bi = i; }
        }
        for (int off = 1; off < 64; off <<= 1) {
            float ov = __shfl_xor(bv, off);
            int   oi = __shfl_xor(bi, off);
            if (ov > bv || (ov == bv && oi < bi)) { bv = ov; bi = oi; }
        }
        int w = tid >> 6;
        if ((tid & 63) == 0) { rv[w] = bv; ri[w] = bi; }
        __syncthreads();
        if (tid == 0) {
            float fv = rv[0]; int fi = ri[0];
            for (int w2 = 1; w2 < 4; ++w2)
                if (rv[w2] > fv || (rv[w2] == fv && ri[w2] < fi)) { fv = rv[w2]; fi = ri[w2]; }
            TopIdx[bh * UU + it] = fi;
            vals[fi] = -1e30f;
        }
        __syncthreads();
    }
}

// ============ kernel C: Vmean[bh,d] += partial sums (atomic) ============
__global__ __launch_bounds__(256) void kC_vmean(
    const float* __restrict__ V, float* __restrict__ Vmean)
{
    int bh = blockIdx.x >> 3;        // 0..63
    int ch = blockIdx.x & 7;         // 8 chunks of 256 rows
    int b = bh >> 3, h = bh & 7;
    int tid = threadIdx.x;
    int d = tid & 63, lg = tid >> 6; // 4 row-groups

    float s = 0.f;
    size_t base = ((size_t)b * LL + ch * 256) * HD + h * DD + d;
    for (int l = lg; l < 256; l += 4) s += V[base + (size_t)l * HD];

    __shared__ float red[256];
    red[tid] = s;
    __syncthreads();
    if (tid < 64) {
        float t = red[tid] + red[tid + 64] + red[tid + 128] + red[tid + 192];
        atomicAdd(&Vmean[bh * DD + d], t);
    }
}

// ============ kernel D: fill all output rows with Vmean/L ============
__global__ __launch_bounds__(256) void kD_fill(
    const float* __restrict__ Vmean, float* __restrict__ out)
{
    size_t i4 = (size_t)blockIdx.x * 256 + threadIdx.x; // float4 index
    size_t o = i4 * 4;
    int hd = (int)(o & (HD - 1));
    int b  = (int)(o >> 20);         // / (L*HD) = 2^20
    int h  = hd >> 6;
    float4 v = *(const float4*)(Vmean + (b * HH + h) * DD + (hd & 63));
    const float sc = 1.0f / LL;
    float4 r; r.x = v.x * sc; r.y = v.y * sc; r.z = v.z * sc; r.w = v.w * sc;
    *(float4*)(out + o) = r;
}

// ============ kernel E: flash-decode partials for the 40 selected queries ============
// grid = (NCHUNK, B*H), block = 256
__global__ __launch_bounds__(256) void kE_attn_partial(
    const float* __restrict__ Q, const float* __restrict__ K, const float* __restrict__ V,
    const int* __restrict__ TopIdx,
    float* __restrict__ Opart, float* __restrict__ mpart, float* __restrict__ spart)
{
    int c  = blockIdx.x;   // key chunk
    int bh = blockIdx.y;
    int b = bh >> 3, h = bh & 7;
    int tid = threadIdx.x;

    __shared__ float Qs[UU * DD];          // 10 KB
    __shared__ float Ks[CHUNK * DD];       // 32 KB (reused for V)
    __shared__ float P[CHUNK * 41];        // 21 KB, stride 41 (odd -> conflict-free)
    __shared__ int   qidx[UU];
    __shared__ float mred[UU], sred[UU];

    if (tid < UU) qidx[tid] = TopIdx[bh * UU + tid];
    __syncthreads();

    size_t hbase  = (size_t)b * LL * HD + h * DD;
    size_t kcbase = hbase + (size_t)c * CHUNK * HD;

    // stage Q rows (40x64) and K chunk (128x64)
    for (int r = tid; r < UU * 16; r += 256) {
        int u = r >> 4, j = r & 15;
        *(float4*)(Qs + u * DD + j * 4) =
            *(const float4*)(Q + hbase + (size_t)qidx[u] * HD + j * 4);
    }
    for (int r = tid; r < CHUNK * 16; r += 256) {
        int l = r >> 4, j = r & 15;
        *(float4*)(Ks + l * DD + j * 4) =
            *(const float4*)(K + kcbase + (size_t)l * HD + j * 4);
    }
    __syncthreads();

    // scores: thread = (l = tid&127, ug = tid>>7); K row cached in regs, reused for 20 u's
    {
        int l = tid & (CHUNK - 1), ug = tid >> 7;
        float4 kr[16];
#pragma unroll
        for (int j = 0; j < 16; ++j) kr[j] = *(const float4*)(Ks + l * DD + j * 4);
#pragma unroll
        for (int uu = 0; uu < 20; ++uu) {
            int u = ug * 20 + uu;
            float dot = 0.f;
#pragma unroll
            for (int j = 0; j < 16; ++j) {
                float4 qv = *(const float4*)(Qs + u * DD + j * 4);
                dot += qv.x * kr[j].x + qv.y * kr[j].y + qv.z * kr[j].z + qv.w * kr[j].w;
            }
            P[l * 41 + u] = dot * 0.125f;  // 1/sqrt(64)
        }
    }
    __syncthreads();

    // per-u chunk max
    if (tid < 160) {
        int u = tid >> 2, part = tid & 3;
        float m = -1e30f;
        for (int l = part * 32; l < part * 32 + 32; ++l) m = fmaxf(m, P[l * 41 + u]);
        m = fmaxf(m, __shfl_xor(m, 1));
        m = fmaxf(m, __shfl_xor(m, 2));
        if (part == 0) mred[u] = m;
    }
    __syncthreads();
    // exp + per-u chunk sum
    if (tid < 160) {
        int u = tid >> 2, part = tid & 3;
        float m = mred[u];
        float s = 0.f;
        for (int l = part * 32; l < part * 32 + 32; ++l) {
            float p = __expf(P[l * 41 + u] - m);
            P[l * 41 + u] = p;
            s += p;
        }
        s += __shfl_xor(s, 1);
        s += __shfl_xor(s, 2);
        if (part == 0) sred[u] = s;
    }
    __syncthreads();

    // stage V chunk into Ks buffer
    for (int r = tid; r < CHUNK * 16; r += 256) {
        int l = r >> 4, j = r & 15;
        *(float4*)(Ks + l * DD + j * 4) =
            *(const float4*)(V + kcbase + (size_t)l * HD + j * 4);
    }
    __syncthreads();

    // PV: thread = (ug2 = tid>>5 in 0..7, d2 = tid&31); 5 u's x 2 d's per thread
    {
        int d2 = tid & 31, ug2 = tid >> 5;
        float acc[5][2];
#pragma unroll
        for (int i = 0; i < 5; ++i) { acc[i][0] = 0.f; acc[i][1] = 0.f; }
        for (int l = 0; l < CHUNK; ++l) {
            float v0 = Ks[l * DD + d2 * 2];
            float v1 = Ks[l * DD + d2 * 2 + 1];
#pragma unroll
            for (int i = 0; i < 5; ++i) {
                float p = P[l * 41 + ug2 + i * 8];
                acc[i][0] += p * v0;
                acc[i][1] += p * v1;
            }
        }
#pragma unroll
        for (int i = 0; i < 5; ++i) {
            int u = ug2 + i * 8;
            size_t ob = (((size_t)(bh * UU + u)) * NCHUNK + c) * DD + d2 * 2;
            float2 st; st.x = acc[i][0]; st.y = acc[i][1];
            *(float2*)(Opart + ob) = st;
        }
    }
    if (tid < UU) {
        mpart[(bh * UU + tid) * NCHUNK + c] = mred[tid];
        spart[(bh * UU + tid) * NCHUNK + c] = sred[tid];
    }
}

// ============ kernel F: combine chunk partials, scatter into output ============
__global__ __launch_bounds__(64) void kF_combine(
    const float* __restrict__ Opart, const float* __restrict__ mpart,
    const float* __restrict__ spart, const int* __restrict__ TopIdx,
    float* __restrict__ out)
{
    int g = blockIdx.x;            // bh*40 + u
    int bh = g / UU;
    int b = bh >> 3, h = bh & 7;
    int d = threadIdx.x;

    float m_i[NCHUNK];
    float Mx = -1e30f;
#pragma unroll
    for (int i = 0; i < NCHUNK; ++i) { m_i[i] = mpart[g * NCHUNK + i]; Mx = fmaxf(Mx, m_i[i]); }
    float S = 0.f, O = 0.f;
#pragma unroll
    for (int i = 0; i < NCHUNK; ++i) {
        float w = __expf(m_i[i] - Mx);
        S += w * spart[g * NCHUNK + i];
        O += w * Opart[((size_t)g * NCHUNK + i) * DD + d];
    }
    int qi = TopIdx[g];
    out[((size_t)b * LL + qi) * HD + h * DD + d] = O / S;
}

extern "C" void kernel_launch(void* const* d_in, const int* in_sizes, int n_in,
                              void* d_out, int out_size, void* d_ws, size_t ws_size,
                              hipStream_t stream) {
    const float* Q  = (const float*)d_in[0];
    const float* K  = (const float*)d_in[1];
    const float* V  = (const float*)d_in[2];
    const int*   IS = (const int*)d_in[3];
    float* out = (float*)d_out;
    char* ws = (char*)d_ws;

    float* M      = (float*)(ws + OFF_M);
    int*   TopIdx = (int*)(ws + OFF_TOP);
    float* Vmean  = (float*)(ws + OFF_VMEAN);
    float* mpart  = (float*)(ws + OFF_MPART);
    float* spart  = (float*)(ws + OFF_SPART);
    float* Opart  = (float*)(ws + OFF_OPART);

    // zero the atomic Vmean accumulator (ws is poisoned each call)
    hipMemsetAsync(Vmean, 0, BB * HH * DD * sizeof(float), stream);

    kA_sample_scores<<<BB * LL, 128, 0, stream>>>(Q, K, IS, M);
    kC_vmean<<<BB * HH * 8, 256, 0, stream>>>(V, Vmean);
    kB_topk<<<BB * HH, 256, 0, stream>>>(M, TopIdx);
    kD_fill<<<(BB * LL * HD) / (256 * 4), 256, 0, stream>>>(Vmean, out);
    kE_attn_partial<<<dim3(NCHUNK, BB * HH), 256, 0, stream>>>(Q, K, V, TopIdx,
                                                               Opart, mpart, spart);
    kF_combine<<<BB * HH * UU, 64, 0, stream>>>(Opart, mpart, spart, TopIdx, out);
}